// Round 5
// baseline (296.221 us; speedup 1.0000x reference)
//
#include <hip/hip_runtime.h>

// GCN(2 layers, 7 nodes) + linear head + KAN (56 per-feature MLPs) + g-MLP, fused.
// B = 32768. Block = 896 threads = 14 waves, 64 batch elements (lane = elem).
// Each wave owns exactly 4 of the 56 KAN feature nets (k wave-uniform -> s_load).
// Phase E writes only scalar phi outputs to LDS (phs) -- no wide per-wave
// accumulators -> ~45 live VGPRs, no spills (round-3 had 30 MB of scratch
// writebacks from 130 live floats squeezed into 64 VGPRs).
// g1/lin1 projections are done as a tiny LDS GEMM phase (F1).
// LDS ~46 KB -> 2 blocks/CU = 28 waves/CU = 87.5% occupancy.

#define NB 32768
#define ELEMS 64
#define FS 57            // 56 floats per elem, pad to 57 (odd -> conflict-free)
#define REG (ELEMS * FS) // 3648 floats per slot

__global__ __launch_bounds__(896, 7)
void gcn_kan_fused(const float* __restrict__ x,
                   const int*   __restrict__ edge,
                   const float* __restrict__ gcn1_w, const float* __restrict__ gcn1_b,
                   const float* __restrict__ gcn2_w, const float* __restrict__ gcn2_b,
                   const float* __restrict__ phi_w1, const float* __restrict__ phi_b1,
                   const float* __restrict__ phi_w2, const float* __restrict__ phi_b2,
                   const float* __restrict__ phi_w3, const float* __restrict__ phi_b3,
                   const float* __restrict__ g_w1,   const float* __restrict__ g_b1,
                   const float* __restrict__ g_w2,   const float* __restrict__ g_b2,
                   const float* __restrict__ g_w3,   const float* __restrict__ g_b3,
                   const float* __restrict__ line_w1,const float* __restrict__ line_b1,
                   const float* __restrict__ line_w2,const float* __restrict__ line_b2,
                   float* __restrict__ out)
{
    __shared__ float sU[3 * REG];     // 43776 B: slot0 y/u/phs, slot1 h1/sflat, slot2 accs
    __shared__ float w1s[128], b1s[8], w2s[64], b2s[8];
    __shared__ float Ahs[49], dinvs[7];
    __shared__ float kanp[5 * 64];    // 4 kan partials + 1 lin per elem

    float* y     = sU;                // [64][57] slot 0
    float* h1    = sU + REG;          // [64][57] slot 1
    float* u     = sU;                // slot 0 (y dead)
    float* sflat = sU + REG;          // slot 1 (h1 dead)
    float* phs   = sU;                // slot 0 (u dead)
    float* accs  = sU + 2 * REG;      // slot 2

    const int t    = threadIdx.x;
    const int lane = t & 63;
    const int wave = t >> 6;          // 0..13
    const int e0   = blockIdx.x * ELEMS;

    // ---- stage small weights + adjacency identity ----
    if (t < 128) w1s[t] = gcn1_w[t];
    if (t < 64)  w2s[t] = gcn2_w[t];
    if (t < 8)  { b1s[t] = gcn1_b[t]; b2s[t] = gcn2_b[t]; }
    if (t < 49)  Ahs[t] = ((t / 7) == (t % 7)) ? 1.0f : 0.0f;
    __syncthreads();

    // ---- edge scatter (benign duplicate stores of 1.0) ----
    if (t < 14) Ahs[edge[14 + t] * 7 + edge[t]] = 1.0f;   // A[dst][src] = 1

    // ---- Phase A: y = x . W1 per (elem,node); coalesced 64B/thread ----
    if (t < 448) {
        const int e = t / 7, m = t - e * 7;
        const float4* xp4 = (const float4*)(x + ((size_t)e0 * 7 + t) * 16);
        float xv[16];
        #pragma unroll
        for (int j = 0; j < 4; ++j) {
            float4 v = xp4[j];
            xv[j*4+0] = v.x; xv[j*4+1] = v.y; xv[j*4+2] = v.z; xv[j*4+3] = v.w;
        }
        #pragma unroll
        for (int c = 0; c < 8; ++c) {
            float s = 0.f;
            #pragma unroll
            for (int f = 0; f < 16; ++f) s = fmaf(xv[f], w1s[f * 8 + c], s);
            y[e * FS + m * 8 + c] = s;
        }
    }
    __syncthreads();

    // ---- adjacency normalization ----
    if (t < 7) {
        float s = 0.f;
        #pragma unroll
        for (int m = 0; m < 7; ++m) s += Ahs[t * 7 + m];
        dinvs[t] = rsqrtf(s);
    }
    __syncthreads();
    if (t < 49) Ahs[t] *= dinvs[t / 7] * dinvs[t % 7];
    __syncthreads();

    // ---- Phase C: h1[e][n] = relu(sum_m A[n,m] y[e][m] + b1) ----
    if (t < 448) {
        const int e = t / 7, n = t - e * 7;
        #pragma unroll
        for (int c = 0; c < 8; ++c) {
            float s = b1s[c];
            #pragma unroll
            for (int m = 0; m < 7; ++m)
                s = fmaf(Ahs[n * 7 + m], y[e * FS + m * 8 + c], s);
            h1[e * FS + n * 8 + c] = fmaxf(s, 0.f);
        }
    }
    __syncthreads();   // y dead -> u may overwrite slot 0

    // ---- Phase D1: u[e][m] = h1[e][m] . W2 ----
    if (t < 448) {
        const int e = t / 7, m = t - e * 7;
        float hv[8];
        #pragma unroll
        for (int c = 0; c < 8; ++c) hv[c] = h1[e * FS + m * 8 + c];
        #pragma unroll
        for (int o = 0; o < 8; ++o) {
            float s = 0.f;
            #pragma unroll
            for (int c = 0; c < 8; ++c) s = fmaf(hv[c], w2s[c * 8 + o], s);
            u[e * FS + m * 8 + o] = s;
        }
    }
    __syncthreads();

    // ---- Phase D2: sflat[e][n] = relu(sum_m A[n,m] u[e][m] + b2) ----
    if (t < 448) {
        const int e = t / 7, n = t - e * 7;
        #pragma unroll
        for (int o = 0; o < 8; ++o) {
            float s = b2s[o];
            #pragma unroll
            for (int m = 0; m < 7; ++m)
                s = fmaf(Ahs[n * 7 + m], u[e * FS + m * 8 + o], s);
            sflat[e * FS + n * 8 + o] = fmaxf(s, 0.f);
        }
    }
    __syncthreads();   // u dead -> phs may overwrite slot 0

    // ---- Phase E: KAN phi-nets, 4 k's per wave, only scalar ph to LDS ----
    {
        const int kbase = __builtin_amdgcn_readfirstlane(wave * 4);
        #pragma unroll 1
        for (int kk = 0; kk < 4; ++kk) {
            const int k = kbase + kk;                 // wave-uniform (SGPR)
            const float f = sflat[lane * FS + k];

            const float* __restrict__ w1k = phi_w1 + k * 32;
            const float* __restrict__ bk1 = phi_b1 + k * 32;
            const float* __restrict__ w2k = phi_w2 + k * 1024;

            float p2[32];
            #pragma unroll
            for (int o = 0; o < 32; ++o) p2[o] = phi_b2[k * 32 + o];

            #pragma unroll 4
            for (int i = 0; i < 32; ++i) {
                const float a = fmaxf(fmaf(f, w1k[i], bk1[i]), 0.f);  // phi1 folded
                #pragma unroll
                for (int o = 0; o < 32; ++o)
                    p2[o] = fmaf(a, w2k[i * 32 + o], p2[o]);
            }

            float ph = phi_b3[k];
            #pragma unroll
            for (int o = 0; o < 32; ++o)
                ph = fmaf(fmaxf(p2[o], 0.f), phi_w3[k * 32 + o], ph);

            phs[lane * FS + k] = ph;
        }
    }
    __syncthreads();

    // ---- Phase F1: accs[e][j] = phi . g_w1 (j<32) | sflat . line_w1 (j>=32) ----
    {
        const int e = t / 14, grp = t - e * 14;       // 64 elems x 14 groups
        #pragma unroll
        for (int jj = 0; jj < 4; ++jj) {
            const int j = grp * 4 + jj;               // 0..55
            float s = 0.f;
            if (j < 32) {
                #pragma unroll 8
                for (int k = 0; k < 56; ++k)
                    s = fmaf(phs[e * FS + k], g_w1[k * 32 + j], s);
            } else {
                const int jl = j - 32;
                #pragma unroll 8
                for (int k = 0; k < 56; ++k)
                    s = fmaf(sflat[e * FS + k], line_w1[k * 24 + jl], s);
            }
            accs[e * FS + j] = s;
        }
    }
    __syncthreads();

    // ---- Phase G: g-MLP (waves 0-3 split o) + linear head (wave 4) ----
    if (wave < 4) {
        const int ow = __builtin_amdgcn_readfirstlane(wave) * 8;
        const float* acc = accs + lane * FS;
        float g1[32];
        #pragma unroll
        for (int i = 0; i < 32; ++i) g1[i] = fmaxf(acc[i] + g_b1[i], 0.f);
        float kp = 0.f;
        #pragma unroll
        for (int oo = 0; oo < 8; ++oo) {
            const int o = ow + oo;                    // wave-uniform
            float s = g_b2[o];
            #pragma unroll
            for (int i = 0; i < 32; ++i) s = fmaf(g1[i], g_w2[i * 32 + o], s);
            kp = fmaf(fmaxf(s, 0.f), g_w3[o], kp);
        }
        kanp[wave * 64 + lane] = kp;
    } else if (wave == 4) {
        const float* acc = accs + lane * FS;
        float lin = line_b2[0];
        #pragma unroll
        for (int j = 0; j < 24; ++j)
            lin = fmaf(fmaxf(acc[32 + j] + line_b1[j], 0.f), line_w2[j], lin);
        kanp[4 * 64 + lane] = lin;
    }
    __syncthreads();

    if (wave == 0) {
        float kan = g_b3[0] + kanp[lane] + kanp[64 + lane]
                  + kanp[128 + lane] + kanp[192 + lane];
        out[e0 + lane] = 0.5f * (kanp[256 + lane] + kan);
    }
}

extern "C" void kernel_launch(void* const* d_in, const int* in_sizes, int n_in,
                              void* d_out, int out_size, void* d_ws, size_t ws_size,
                              hipStream_t stream) {
    const float* x       = (const float*)d_in[0];
    const int*   edge    = (const int*)  d_in[1];
    const float* gcn1_w  = (const float*)d_in[2];
    const float* gcn1_b  = (const float*)d_in[3];
    const float* gcn2_w  = (const float*)d_in[4];
    const float* gcn2_b  = (const float*)d_in[5];
    const float* phi_w1  = (const float*)d_in[6];
    const float* phi_b1  = (const float*)d_in[7];
    const float* phi_w2  = (const float*)d_in[8];
    const float* phi_b2  = (const float*)d_in[9];
    const float* phi_w3  = (const float*)d_in[10];
    const float* phi_b3  = (const float*)d_in[11];
    const float* g_w1    = (const float*)d_in[12];
    const float* g_b1    = (const float*)d_in[13];
    const float* g_w2    = (const float*)d_in[14];
    const float* g_b2    = (const float*)d_in[15];
    const float* g_w3    = (const float*)d_in[16];
    const float* g_b3    = (const float*)d_in[17];
    const float* line_w1 = (const float*)d_in[18];
    const float* line_b1 = (const float*)d_in[19];
    const float* line_w2 = (const float*)d_in[20];
    const float* line_b2 = (const float*)d_in[21];
    float* out = (float*)d_out;

    dim3 grid(NB / ELEMS);   // 512 blocks
    dim3 block(896);         // 14 waves, 4 k's each
    gcn_kan_fused<<<grid, block, 0, stream>>>(
        x, edge, gcn1_w, gcn1_b, gcn2_w, gcn2_b,
        phi_w1, phi_b1, phi_w2, phi_b2, phi_w3, phi_b3,
        g_w1, g_b1, g_w2, g_b2, g_w3, g_b3,
        line_w1, line_b1, line_w2, line_b2, out);
}

// Round 6
// 243.872 us; speedup vs baseline: 1.2147x; 1.2147x over previous
//
#include <hip/hip_runtime.h>

// 3-kernel split. B = 32768.
// K1: GCN (2 layers) -> sflatT [56][B] in workspace (transposed, coalesced).
// K2: 56 per-feature phi MLPs. One k per block, w2 staged in LDS (4KB) and
//     reused by 512 elems -> removes the s_load SMEM serialization that kept
//     rounds 3/5 at 22-26% VALUBusy. Inner loop: broadcast ds_read_b128 + FMA.
// K3: g1/lin1 projections + g-MLP + linear head, LDS-staged weights.
// Workspace: sflatT (7.34 MB) + phsT (7.34 MB).

#define NB 32768
#define FS 57   // 56 + 1 pad

// ---------------- Kernel 1: GCN -> sflatT ----------------
__global__ __launch_bounds__(448, 4)
void k1_gcn(const float* __restrict__ x, const int* __restrict__ edge,
            const float* __restrict__ gcn1_w, const float* __restrict__ gcn1_b,
            const float* __restrict__ gcn2_w, const float* __restrict__ gcn2_b,
            float* __restrict__ sflatT)
{
    __shared__ float sA[64 * FS];    // y, then u
    __shared__ float sB[64 * FS];    // h1, then sflat
    __shared__ float w1s[128], b1s[8], w2s[64], b2s[8];
    __shared__ float Ahs[49], dinvs[7];

    const int t = threadIdx.x;
    const int lane = t & 63, wave = t >> 6;   // 7 waves
    const int e0 = blockIdx.x * 64;
    const int e = t / 7, n = t - e * 7;       // t < 448 always

    if (t < 128) w1s[t] = gcn1_w[t];
    else if (t < 192) w2s[t - 128] = gcn2_w[t - 128];
    else if (t < 200) b1s[t - 192] = gcn1_b[t - 192];
    else if (t < 208) b2s[t - 200] = gcn2_b[t - 200];
    else if (t < 257) { int q = t - 208; Ahs[q] = ((q / 7) == (q % 7)) ? 1.f : 0.f; }
    __syncthreads();
    if (t < 14) Ahs[edge[14 + t] * 7 + edge[t]] = 1.f;   // benign duplicates

    // Phase A: y[e][m][:] = x[e][m][:] . W1   (m == n here)
    {
        const float4* xp4 = (const float4*)(x + ((size_t)e0 * 7 + t) * 16);
        float xv[16];
        #pragma unroll
        for (int j = 0; j < 4; ++j) {
            float4 v = xp4[j];
            xv[j*4+0] = v.x; xv[j*4+1] = v.y; xv[j*4+2] = v.z; xv[j*4+3] = v.w;
        }
        #pragma unroll
        for (int c = 0; c < 8; ++c) {
            float s = 0.f;
            #pragma unroll
            for (int f = 0; f < 16; ++f) s = fmaf(xv[f], w1s[f * 8 + c], s);
            sA[e * FS + n * 8 + c] = s;
        }
    }
    __syncthreads();

    if (t < 7) {
        float s = 0.f;
        #pragma unroll
        for (int m = 0; m < 7; ++m) s += Ahs[t * 7 + m];
        dinvs[t] = rsqrtf(s);
    }
    __syncthreads();
    if (t < 49) Ahs[t] *= dinvs[t / 7] * dinvs[t % 7];
    __syncthreads();

    // Phase C: h1[e][n] = relu(sum_m A[n,m] y[e][m] + b1)
    #pragma unroll
    for (int c = 0; c < 8; ++c) {
        float s = b1s[c];
        #pragma unroll
        for (int m = 0; m < 7; ++m)
            s = fmaf(Ahs[n * 7 + m], sA[e * FS + m * 8 + c], s);
        sB[e * FS + n * 8 + c] = fmaxf(s, 0.f);
    }
    __syncthreads();   // y dead

    // Phase D1: u[e][m] = h1[e][m] . W2
    {
        float hv[8];
        #pragma unroll
        for (int c = 0; c < 8; ++c) hv[c] = sB[e * FS + n * 8 + c];
        #pragma unroll
        for (int o = 0; o < 8; ++o) {
            float s = 0.f;
            #pragma unroll
            for (int c = 0; c < 8; ++c) s = fmaf(hv[c], w2s[c * 8 + o], s);
            sA[e * FS + n * 8 + o] = s;
        }
    }
    __syncthreads();

    // Phase D2: sflat[e][n] = relu(sum_m A[n,m] u[e][m] + b2)
    #pragma unroll
    for (int o = 0; o < 8; ++o) {
        float s = b2s[o];
        #pragma unroll
        for (int m = 0; m < 7; ++m)
            s = fmaf(Ahs[n * 7 + m], sA[e * FS + m * 8 + o], s);
        sB[e * FS + n * 8 + o] = fmaxf(s, 0.f);
    }
    __syncthreads();

    // Write-out transposed: wave w covers rows j = p*7 + w, fully coalesced.
    #pragma unroll
    for (int p = 0; p < 8; ++p) {
        const int j = p * 7 + wave;   // 0..55
        sflatT[(size_t)j * NB + e0 + lane] = sB[lane * FS + j];
    }
}

// ---------------- Kernel 2: phi MLPs (one k per block) ----------------
__global__ __launch_bounds__(256, 5)
void k2_phi(const float* __restrict__ phi_w1, const float* __restrict__ phi_b1,
            const float* __restrict__ phi_w2, const float* __restrict__ phi_b2,
            const float* __restrict__ phi_w3, const float* __restrict__ phi_b3,
            const float* __restrict__ sflatT, float* __restrict__ phsT)
{
    __shared__ float w2s[1024];
    __shared__ float w1s[32], b1s[32], b2s[32], w3s[32];
    __shared__ float b3s;

    const int t = threadIdx.x;
    const int c = blockIdx.x;        // elem chunk 0..63
    const int k = blockIdx.y;        // feature net 0..55

    // Stage weights once (coalesced)
    ((float4*)w2s)[t] = ((const float4*)(phi_w2 + k * 1024))[t];
    if (t < 32)            w1s[t]      = phi_w1[k * 32 + t];
    else if (t < 64)       b1s[t - 32] = phi_b1[k * 32 + t - 32];
    else if (t < 96)       b2s[t - 64] = phi_b2[k * 32 + t - 64];
    else if (t < 128)      w3s[t - 96] = phi_w3[k * 32 + t - 96];
    else if (t == 128)     b3s         = phi_b3[k];

    const int eA = c * 512 + t;      // two elems per thread
    const float f0 = sflatT[(size_t)k * NB + eA];
    const float f1 = sflatT[(size_t)k * NB + eA + 256];
    __syncthreads();

    float p2a[32], p2b[32];
    #pragma unroll
    for (int o = 0; o < 32; ++o) { p2a[o] = 0.f; p2b[o] = 0.f; }

    #pragma unroll 4
    for (int i = 0; i < 32; ++i) {
        const float w1i = w1s[i], b1i = b1s[i];
        const float a0 = fmaxf(fmaf(f0, w1i, b1i), 0.f);   // phi1 folded
        const float a1 = fmaxf(fmaf(f1, w1i, b1i), 0.f);
        const float4* wrow = (const float4*)(w2s + i * 32); // broadcast reads
        #pragma unroll
        for (int oc = 0; oc < 8; ++oc) {
            const float4 w4 = wrow[oc];
            p2a[oc*4+0] = fmaf(a0, w4.x, p2a[oc*4+0]);
            p2a[oc*4+1] = fmaf(a0, w4.y, p2a[oc*4+1]);
            p2a[oc*4+2] = fmaf(a0, w4.z, p2a[oc*4+2]);
            p2a[oc*4+3] = fmaf(a0, w4.w, p2a[oc*4+3]);
            p2b[oc*4+0] = fmaf(a1, w4.x, p2b[oc*4+0]);
            p2b[oc*4+1] = fmaf(a1, w4.y, p2b[oc*4+1]);
            p2b[oc*4+2] = fmaf(a1, w4.z, p2b[oc*4+2]);
            p2b[oc*4+3] = fmaf(a1, w4.w, p2b[oc*4+3]);
        }
    }

    float pha = b3s, phb = b3s;
    #pragma unroll
    for (int o = 0; o < 32; ++o) {
        const float w3o = w3s[o], b2o = b2s[o];
        pha = fmaf(fmaxf(p2a[o] + b2o, 0.f), w3o, pha);
        phb = fmaf(fmaxf(p2b[o] + b2o, 0.f), w3o, phb);
    }
    phsT[(size_t)k * NB + eA]       = pha;
    phsT[(size_t)k * NB + eA + 256] = phb;
}

// ---------------- Kernel 3: projections + g-MLP + linear head ----------------
__global__ __launch_bounds__(128, 4)
void k3_head(const float* __restrict__ g_w1,   const float* __restrict__ g_b1,
             const float* __restrict__ g_w2,   const float* __restrict__ g_b2,
             const float* __restrict__ g_w3,   const float* __restrict__ g_b3,
             const float* __restrict__ line_w1,const float* __restrict__ line_b1,
             const float* __restrict__ line_w2,const float* __restrict__ line_b2,
             const float* __restrict__ sflatT, const float* __restrict__ phsT,
             float* __restrict__ out)
{
    __shared__ float gw1s[56 * 32];
    __shared__ float lw1s[56 * 24];
    __shared__ float gw2s[32 * 32];
    __shared__ float gb1s[32], gb2s[32], gw3s[32], lb1s[24], lw2s[24];
    __shared__ float gb3s, lb2s;

    const int t = threadIdx.x;
    const int e = blockIdx.x * 128 + t;

    for (int i = t; i < 1792; i += 128) gw1s[i] = g_w1[i];
    for (int i = t; i < 1344; i += 128) lw1s[i] = line_w1[i];
    for (int i = t; i < 1024; i += 128) gw2s[i] = g_w2[i];
    if (t < 32) { gb1s[t] = g_b1[t]; gb2s[t] = g_b2[t]; gw3s[t] = g_w3[t]; }
    else if (t < 56) { lb1s[t - 32] = line_b1[t - 32]; lw2s[t - 32] = line_w2[t - 32]; }
    else if (t == 56) { gb3s = g_b3[0]; lb2s = line_b2[0]; }
    __syncthreads();

    float g1p[32], l1p[24];
    #pragma unroll
    for (int j = 0; j < 32; ++j) g1p[j] = 0.f;
    #pragma unroll
    for (int j = 0; j < 24; ++j) l1p[j] = 0.f;

    #pragma unroll 2
    for (int k = 0; k < 56; ++k) {
        const float ph = phsT[(size_t)k * NB + e];
        const float f  = sflatT[(size_t)k * NB + e];
        const float4* gr = (const float4*)(gw1s + k * 32);
        #pragma unroll
        for (int jc = 0; jc < 8; ++jc) {
            const float4 w = gr[jc];
            g1p[jc*4+0] = fmaf(ph, w.x, g1p[jc*4+0]);
            g1p[jc*4+1] = fmaf(ph, w.y, g1p[jc*4+1]);
            g1p[jc*4+2] = fmaf(ph, w.z, g1p[jc*4+2]);
            g1p[jc*4+3] = fmaf(ph, w.w, g1p[jc*4+3]);
        }
        const float4* lr = (const float4*)(lw1s + k * 24);   // 96B-aligned
        #pragma unroll
        for (int jc = 0; jc < 6; ++jc) {
            const float4 w = lr[jc];
            l1p[jc*4+0] = fmaf(f, w.x, l1p[jc*4+0]);
            l1p[jc*4+1] = fmaf(f, w.y, l1p[jc*4+1]);
            l1p[jc*4+2] = fmaf(f, w.z, l1p[jc*4+2]);
            l1p[jc*4+3] = fmaf(f, w.w, l1p[jc*4+3]);
        }
    }

    // g-MLP layer 1 relu, layer 2 (i-outer with float4 rows), layer 3
    float g1[32];
    #pragma unroll
    for (int i = 0; i < 32; ++i) g1[i] = fmaxf(g1p[i] + gb1s[i], 0.f);
    float s2[32];
    #pragma unroll
    for (int o = 0; o < 32; ++o) s2[o] = 0.f;
    #pragma unroll 4
    for (int i = 0; i < 32; ++i) {
        const float a = g1[i];
        const float4* wr = (const float4*)(gw2s + i * 32);
        #pragma unroll
        for (int oc = 0; oc < 8; ++oc) {
            const float4 w = wr[oc];
            s2[oc*4+0] = fmaf(a, w.x, s2[oc*4+0]);
            s2[oc*4+1] = fmaf(a, w.y, s2[oc*4+1]);
            s2[oc*4+2] = fmaf(a, w.z, s2[oc*4+2]);
            s2[oc*4+3] = fmaf(a, w.w, s2[oc*4+3]);
        }
    }
    float kan = gb3s;
    #pragma unroll
    for (int o = 0; o < 32; ++o)
        kan = fmaf(fmaxf(s2[o] + gb2s[o], 0.f), gw3s[o], kan);

    float lin = lb2s;
    #pragma unroll
    for (int j = 0; j < 24; ++j)
        lin = fmaf(fmaxf(l1p[j] + lb1s[j], 0.f), lw2s[j], lin);

    out[e] = 0.5f * (lin + kan);
}

extern "C" void kernel_launch(void* const* d_in, const int* in_sizes, int n_in,
                              void* d_out, int out_size, void* d_ws, size_t ws_size,
                              hipStream_t stream) {
    const float* x       = (const float*)d_in[0];
    const int*   edge    = (const int*)  d_in[1];
    const float* gcn1_w  = (const float*)d_in[2];
    const float* gcn1_b  = (const float*)d_in[3];
    const float* gcn2_w  = (const float*)d_in[4];
    const float* gcn2_b  = (const float*)d_in[5];
    const float* phi_w1  = (const float*)d_in[6];
    const float* phi_b1  = (const float*)d_in[7];
    const float* phi_w2  = (const float*)d_in[8];
    const float* phi_b2  = (const float*)d_in[9];
    const float* phi_w3  = (const float*)d_in[10];
    const float* phi_b3  = (const float*)d_in[11];
    const float* g_w1    = (const float*)d_in[12];
    const float* g_b1    = (const float*)d_in[13];
    const float* g_w2    = (const float*)d_in[14];
    const float* g_b2    = (const float*)d_in[15];
    const float* g_w3    = (const float*)d_in[16];
    const float* g_b3    = (const float*)d_in[17];
    const float* line_w1 = (const float*)d_in[18];
    const float* line_b1 = (const float*)d_in[19];
    const float* line_w2 = (const float*)d_in[20];
    const float* line_b2 = (const float*)d_in[21];
    float* out = (float*)d_out;

    float* sflatT = (float*)d_ws;                       // [56][NB] = 7.34 MB
    float* phsT   = (float*)d_ws + (size_t)56 * NB;     // [56][NB] = 7.34 MB

    k1_gcn<<<dim3(NB / 64), dim3(448), 0, stream>>>(
        x, edge, gcn1_w, gcn1_b, gcn2_w, gcn2_b, sflatT);

    k2_phi<<<dim3(64, 56), dim3(256), 0, stream>>>(
        phi_w1, phi_b1, phi_w2, phi_b2, phi_w3, phi_b3, sflatT, phsT);

    k3_head<<<dim3(NB / 128), dim3(128), 0, stream>>>(
        g_w1, g_b1, g_w2, g_b2, g_w3, g_b3,
        line_w1, line_b1, line_w2, line_b2, sflatT, phsT, out);
}

// Round 10
// 173.971 us; speedup vs baseline: 1.7027x; 1.4018x over previous
//
#include <hip/hip_runtime.h>

// 3-kernel split. B = 32768.
// K1: GCN (2 layers) -> sflatT [56][B] (transposed, coalesced).
// K2: 56 per-feature phi MLPs, one k per block, w2 LDS-staged (reused 512x).
//     Round-6 lesson: launch_bounds(256,5) capped VGPR at ~96 == live set ->
//     allocator spilled p2a/p2b wholesale (VGPR=48, 21 MB scratch writebacks,
//     VALUBusy 37%). Now (256,4): cap 128, live ~96, headroom -> no spill.
// K3: projections + g-MLP + head. Was 256x128 threads (0.5 waves/SIMD,
//     latency-bound); now 512x256: 64 elems/block, 4 waves split 56 k's,
//     LDS tree-reduce, split tail.

#define NB 32768
#define FS 57   // 56 + 1 pad

// ---------------- Kernel 1: GCN -> sflatT ----------------
__global__ __launch_bounds__(448, 4)
void k1_gcn(const float* __restrict__ x, const int* __restrict__ edge,
            const float* __restrict__ gcn1_w, const float* __restrict__ gcn1_b,
            const float* __restrict__ gcn2_w, const float* __restrict__ gcn2_b,
            float* __restrict__ sflatT)
{
    __shared__ float sA[64 * FS];    // y, then u
    __shared__ float sB[64 * FS];    // h1, then sflat
    __shared__ float w1s[128], b1s[8], w2s[64], b2s[8];
    __shared__ float Ahs[49], dinvs[7];

    const int t = threadIdx.x;
    const int lane = t & 63, wave = t >> 6;   // 7 waves
    const int e0 = blockIdx.x * 64;
    const int e = t / 7, n = t - e * 7;       // t < 448 always

    if (t < 128) w1s[t] = gcn1_w[t];
    else if (t < 192) w2s[t - 128] = gcn2_w[t - 128];
    else if (t < 200) b1s[t - 192] = gcn1_b[t - 192];
    else if (t < 208) b2s[t - 200] = gcn2_b[t - 200];
    else if (t < 257) { int q = t - 208; Ahs[q] = ((q / 7) == (q % 7)) ? 1.f : 0.f; }
    __syncthreads();
    if (t < 14) Ahs[edge[14 + t] * 7 + edge[t]] = 1.f;   // benign duplicates

    // Phase A: y[e][m][:] = x[e][m][:] . W1   (m == n here)
    {
        const float4* xp4 = (const float4*)(x + ((size_t)e0 * 7 + t) * 16);
        float xv[16];
        #pragma unroll
        for (int j = 0; j < 4; ++j) {
            float4 v = xp4[j];
            xv[j*4+0] = v.x; xv[j*4+1] = v.y; xv[j*4+2] = v.z; xv[j*4+3] = v.w;
        }
        #pragma unroll
        for (int c = 0; c < 8; ++c) {
            float s = 0.f;
            #pragma unroll
            for (int f = 0; f < 16; ++f) s = fmaf(xv[f], w1s[f * 8 + c], s);
            sA[e * FS + n * 8 + c] = s;
        }
    }
    __syncthreads();

    if (t < 7) {
        float s = 0.f;
        #pragma unroll
        for (int m = 0; m < 7; ++m) s += Ahs[t * 7 + m];
        dinvs[t] = rsqrtf(s);
    }
    __syncthreads();
    if (t < 49) Ahs[t] *= dinvs[t / 7] * dinvs[t % 7];
    __syncthreads();

    // Phase C: h1[e][n] = relu(sum_m A[n,m] y[e][m] + b1)
    #pragma unroll
    for (int c = 0; c < 8; ++c) {
        float s = b1s[c];
        #pragma unroll
        for (int m = 0; m < 7; ++m)
            s = fmaf(Ahs[n * 7 + m], sA[e * FS + m * 8 + c], s);
        sB[e * FS + n * 8 + c] = fmaxf(s, 0.f);
    }
    __syncthreads();   // y dead

    // Phase D1: u[e][m] = h1[e][m] . W2
    {
        float hv[8];
        #pragma unroll
        for (int c = 0; c < 8; ++c) hv[c] = sB[e * FS + n * 8 + c];
        #pragma unroll
        for (int o = 0; o < 8; ++o) {
            float s = 0.f;
            #pragma unroll
            for (int c = 0; c < 8; ++c) s = fmaf(hv[c], w2s[c * 8 + o], s);
            sA[e * FS + n * 8 + o] = s;
        }
    }
    __syncthreads();

    // Phase D2: sflat[e][n] = relu(sum_m A[n,m] u[e][m] + b2)
    #pragma unroll
    for (int o = 0; o < 8; ++o) {
        float s = b2s[o];
        #pragma unroll
        for (int m = 0; m < 7; ++m)
            s = fmaf(Ahs[n * 7 + m], sA[e * FS + m * 8 + o], s);
        sB[e * FS + n * 8 + o] = fmaxf(s, 0.f);
    }
    __syncthreads();

    // Write-out transposed: wave w covers rows j = p*7 + w, fully coalesced.
    #pragma unroll
    for (int p = 0; p < 8; ++p) {
        const int j = p * 7 + wave;   // 0..55
        sflatT[(size_t)j * NB + e0 + lane] = sB[lane * FS + j];
    }
}

// ---------------- Kernel 2: phi MLPs (one k per block) ----------------
__global__ __launch_bounds__(256, 4)   // VGPR cap 128; live ~96 -> no spill
void k2_phi(const float* __restrict__ phi_w1, const float* __restrict__ phi_b1,
            const float* __restrict__ phi_w2, const float* __restrict__ phi_b2,
            const float* __restrict__ phi_w3, const float* __restrict__ phi_b3,
            const float* __restrict__ sflatT, float* __restrict__ phsT)
{
    __shared__ float w2s[1024];
    __shared__ float w1s[32], b1s[32], b2s[32], w3s[32];
    __shared__ float b3s;

    const int t = threadIdx.x;
    const int c = blockIdx.x;        // elem chunk 0..63
    const int k = blockIdx.y;        // feature net 0..55

    // Stage weights once (coalesced)
    ((float4*)w2s)[t] = ((const float4*)(phi_w2 + k * 1024))[t];
    if (t < 32)            w1s[t]      = phi_w1[k * 32 + t];
    else if (t < 64)       b1s[t - 32] = phi_b1[k * 32 + t - 32];
    else if (t < 96)       b2s[t - 64] = phi_b2[k * 32 + t - 64];
    else if (t < 128)      w3s[t - 96] = phi_w3[k * 32 + t - 96];
    else if (t == 128)     b3s         = phi_b3[k];

    const int eA = c * 512 + t;      // two elems per thread
    const float f0 = sflatT[(size_t)k * NB + eA];
    const float f1 = sflatT[(size_t)k * NB + eA + 256];
    __syncthreads();

    float p2a[32], p2b[32];
    #pragma unroll
    for (int o = 0; o < 32; ++o) { p2a[o] = 0.f; p2b[o] = 0.f; }

    #pragma unroll 2
    for (int i = 0; i < 32; ++i) {
        const float w1i = w1s[i], b1i = b1s[i];
        const float a0 = fmaxf(fmaf(f0, w1i, b1i), 0.f);   // phi1 folded
        const float a1 = fmaxf(fmaf(f1, w1i, b1i), 0.f);
        const float4* wrow = (const float4*)(w2s + i * 32); // broadcast reads
        #pragma unroll
        for (int oc = 0; oc < 8; ++oc) {
            const float4 w4 = wrow[oc];
            p2a[oc*4+0] = fmaf(a0, w4.x, p2a[oc*4+0]);
            p2a[oc*4+1] = fmaf(a0, w4.y, p2a[oc*4+1]);
            p2a[oc*4+2] = fmaf(a0, w4.z, p2a[oc*4+2]);
            p2a[oc*4+3] = fmaf(a0, w4.w, p2a[oc*4+3]);
            p2b[oc*4+0] = fmaf(a1, w4.x, p2b[oc*4+0]);
            p2b[oc*4+1] = fmaf(a1, w4.y, p2b[oc*4+1]);
            p2b[oc*4+2] = fmaf(a1, w4.z, p2b[oc*4+2]);
            p2b[oc*4+3] = fmaf(a1, w4.w, p2b[oc*4+3]);
        }
    }

    float pha = b3s, phb = b3s;
    #pragma unroll
    for (int o = 0; o < 32; ++o) {
        const float w3o = w3s[o], b2o = b2s[o];
        pha = fmaf(fmaxf(p2a[o] + b2o, 0.f), w3o, pha);
        phb = fmaf(fmaxf(p2b[o] + b2o, 0.f), w3o, phb);
    }
    phsT[(size_t)k * NB + eA]       = pha;
    phsT[(size_t)k * NB + eA + 256] = phb;
}

// ---------------- Kernel 3: projections + g-MLP + linear head ----------------
// 512 blocks x 256 threads: 64 elems/block (lane = elem), 4 waves split 56 k's.
__global__ __launch_bounds__(256, 2)
void k3_head(const float* __restrict__ g_w1,   const float* __restrict__ g_b1,
             const float* __restrict__ g_w2,   const float* __restrict__ g_b2,
             const float* __restrict__ g_w3,   const float* __restrict__ g_b3,
             const float* __restrict__ line_w1,const float* __restrict__ line_b1,
             const float* __restrict__ line_w2,const float* __restrict__ line_b2,
             const float* __restrict__ sflatT, const float* __restrict__ phsT,
             float* __restrict__ out)
{
    __shared__ float red[4 * 64 * FS];   // 58368 B partials / accs
    __shared__ float gw1s[56 * 32];
    __shared__ float lw1s[56 * 24];
    __shared__ float gw2s[32 * 32];
    __shared__ float gb1s[32], gb2s[32], gw3s[32], lb1s[24], lw2s[24];
    __shared__ float gb3s, lb2s;
    __shared__ float kanp[5 * 64];

    const int t = threadIdx.x;
    const int lane = t & 63, wave = t >> 6;   // 4 waves
    const int e0 = blockIdx.x * 64;

    for (int i = t; i < 1792; i += 256) gw1s[i] = g_w1[i];
    for (int i = t; i < 1344; i += 256) lw1s[i] = line_w1[i];
    for (int i = t; i < 1024; i += 256) gw2s[i] = g_w2[i];
    if (t < 32) { gb1s[t] = g_b1[t]; gb2s[t] = g_b2[t]; gw3s[t] = g_w3[t]; }
    else if (t < 56) { lb1s[t - 32] = line_b1[t - 32]; lw2s[t - 32] = line_w2[t - 32]; }
    else if (t == 56) { gb3s = g_b3[0]; lb2s = line_b2[0]; }
    __syncthreads();

    // each wave: 14 k's; accumulate g1p/l1p for its lane-elem
    float g1p[32], l1p[24];
    #pragma unroll
    for (int j = 0; j < 32; ++j) g1p[j] = 0.f;
    #pragma unroll
    for (int j = 0; j < 24; ++j) l1p[j] = 0.f;

    const int kb = wave * 14;
    #pragma unroll 2
    for (int kk = 0; kk < 14; ++kk) {
        const int k = kb + kk;
        const float ph = phsT[(size_t)k * NB + e0 + lane];   // coalesced
        const float f  = sflatT[(size_t)k * NB + e0 + lane];
        const float4* gr = (const float4*)(gw1s + k * 32);   // broadcast LDS
        #pragma unroll
        for (int jc = 0; jc < 8; ++jc) {
            const float4 w = gr[jc];
            g1p[jc*4+0] = fmaf(ph, w.x, g1p[jc*4+0]);
            g1p[jc*4+1] = fmaf(ph, w.y, g1p[jc*4+1]);
            g1p[jc*4+2] = fmaf(ph, w.z, g1p[jc*4+2]);
            g1p[jc*4+3] = fmaf(ph, w.w, g1p[jc*4+3]);
        }
        const float4* lr = (const float4*)(lw1s + k * 24);   // 96B-aligned
        #pragma unroll
        for (int jc = 0; jc < 6; ++jc) {
            const float4 w = lr[jc];
            l1p[jc*4+0] = fmaf(f, w.x, l1p[jc*4+0]);
            l1p[jc*4+1] = fmaf(f, w.y, l1p[jc*4+1]);
            l1p[jc*4+2] = fmaf(f, w.z, l1p[jc*4+2]);
            l1p[jc*4+3] = fmaf(f, w.w, l1p[jc*4+3]);
        }
    }

    // write partials
    {
        float* my = red + (wave * 64 + lane) * FS;
        #pragma unroll
        for (int j = 0; j < 32; ++j) my[j] = g1p[j];
        #pragma unroll
        for (int j = 0; j < 24; ++j) my[32 + j] = l1p[j];
    }
    __syncthreads();

    // 4-way sum: thread (e = t>>2, g = t&3) handles 14 j's -> red slot 0
    {
        const int e = t >> 2, g = t & 3;
        #pragma unroll
        for (int jj = 0; jj < 14; ++jj) {
            const int j = g * 14 + jj;
            float s = red[(0 * 64 + e) * FS + j] + red[(1 * 64 + e) * FS + j]
                    + red[(2 * 64 + e) * FS + j] + red[(3 * 64 + e) * FS + j];
            red[e * FS + j] = s;
        }
    }
    __syncthreads();

    // tail: waves 0-3 each do 8 of g2's outputs; wave 0 also the linear head
    {
        const float* acc = red + lane * FS;
        float g1[32];
        #pragma unroll
        for (int i = 0; i < 32; ++i) g1[i] = fmaxf(acc[i] + gb1s[i], 0.f);
        const int ob = wave * 8;
        float kp = 0.f;
        #pragma unroll
        for (int oo = 0; oo < 8; ++oo) {
            const int o = ob + oo;
            float s = gb2s[o];
            #pragma unroll
            for (int i = 0; i < 32; ++i) s = fmaf(g1[i], gw2s[i * 32 + o], s);
            kp = fmaf(fmaxf(s, 0.f), gw3s[o], kp);
        }
        kanp[wave * 64 + lane] = kp;
        if (wave == 0) {
            float lin = lb2s;
            #pragma unroll
            for (int j = 0; j < 24; ++j)
                lin = fmaf(fmaxf(acc[32 + j] + lb1s[j], 0.f), lw2s[j], lin);
            kanp[4 * 64 + lane] = lin;
        }
    }
    __syncthreads();

    if (wave == 0) {
        float kan = gb3s + kanp[lane] + kanp[64 + lane]
                  + kanp[128 + lane] + kanp[192 + lane];
        out[e0 + lane] = 0.5f * (kanp[256 + lane] + kan);
    }
}

extern "C" void kernel_launch(void* const* d_in, const int* in_sizes, int n_in,
                              void* d_out, int out_size, void* d_ws, size_t ws_size,
                              hipStream_t stream) {
    const float* x       = (const float*)d_in[0];
    const int*   edge    = (const int*)  d_in[1];
    const float* gcn1_w  = (const float*)d_in[2];
    const float* gcn1_b  = (const float*)d_in[3];
    const float* gcn2_w  = (const float*)d_in[4];
    const float* gcn2_b  = (const float*)d_in[5];
    const float* phi_w1  = (const float*)d_in[6];
    const float* phi_b1  = (const float*)d_in[7];
    const float* phi_w2  = (const float*)d_in[8];
    const float* phi_b2  = (const float*)d_in[9];
    const float* phi_w3  = (const float*)d_in[10];
    const float* phi_b3  = (const float*)d_in[11];
    const float* g_w1    = (const float*)d_in[12];
    const float* g_b1    = (const float*)d_in[13];
    const float* g_w2    = (const float*)d_in[14];
    const float* g_b2    = (const float*)d_in[15];
    const float* g_w3    = (const float*)d_in[16];
    const float* g_b3    = (const float*)d_in[17];
    const float* line_w1 = (const float*)d_in[18];
    const float* line_b1 = (const float*)d_in[19];
    const float* line_w2 = (const float*)d_in[20];
    const float* line_b2 = (const float*)d_in[21];
    float* out = (float*)d_out;

    float* sflatT = (float*)d_ws;                       // [56][NB] = 7.34 MB
    float* phsT   = (float*)d_ws + (size_t)56 * NB;     // [56][NB] = 7.34 MB

    k1_gcn<<<dim3(NB / 64), dim3(448), 0, stream>>>(
        x, edge, gcn1_w, gcn1_b, gcn2_w, gcn2_b, sflatT);

    k2_phi<<<dim3(64, 56), dim3(256), 0, stream>>>(
        phi_w1, phi_b1, phi_w2, phi_b2, phi_w3, phi_b3, sflatT, phsT);

    k3_head<<<dim3(NB / 64), dim3(256), 0, stream>>>(
        g_w1, g_b1, g_w2, g_b2, g_w3, g_b3,
        line_w1, line_b1, line_w2, line_b2, sflatT, phsT, out);
}

// Round 11
// 170.191 us; speedup vs baseline: 1.7405x; 1.0222x over previous
//
#include <hip/hip_runtime.h>

// 3-kernel split. B = 32768.
// K1: GCN (2 layers) -> sflatT [56][B] (transposed, coalesced).
// K2: 56 per-feature phi MLPs, one k per block, w2 LDS-staged.
//     Round-10 pmc: 2 elems/thread = 8 FMA per ds_read_b128 -> CU-shared LDS
//     pipe 1.25x oversubscribed at 16 waves/CU (VALUBusy 70%). Now 4 elems/
//     thread = 16 FMA/read; live ~150 VGPR -> launch_bounds(256,3) cap ~170.
// K3: projections + g-MLP + head (unchanged this round).

#define NB 32768
#define FS 57   // 56 + 1 pad

// ---------------- Kernel 1: GCN -> sflatT ----------------
__global__ __launch_bounds__(448, 4)
void k1_gcn(const float* __restrict__ x, const int* __restrict__ edge,
            const float* __restrict__ gcn1_w, const float* __restrict__ gcn1_b,
            const float* __restrict__ gcn2_w, const float* __restrict__ gcn2_b,
            float* __restrict__ sflatT)
{
    __shared__ float sA[64 * FS];    // y, then u
    __shared__ float sB[64 * FS];    // h1, then sflat
    __shared__ float w1s[128], b1s[8], w2s[64], b2s[8];
    __shared__ float Ahs[49], dinvs[7];

    const int t = threadIdx.x;
    const int lane = t & 63, wave = t >> 6;   // 7 waves
    const int e0 = blockIdx.x * 64;
    const int e = t / 7, n = t - e * 7;       // t < 448 always

    if (t < 128) w1s[t] = gcn1_w[t];
    else if (t < 192) w2s[t - 128] = gcn2_w[t - 128];
    else if (t < 200) b1s[t - 192] = gcn1_b[t - 192];
    else if (t < 208) b2s[t - 200] = gcn2_b[t - 200];
    else if (t < 257) { int q = t - 208; Ahs[q] = ((q / 7) == (q % 7)) ? 1.f : 0.f; }
    __syncthreads();
    if (t < 14) Ahs[edge[14 + t] * 7 + edge[t]] = 1.f;   // benign duplicates

    // Phase A: y[e][m][:] = x[e][m][:] . W1   (m == n here)
    {
        const float4* xp4 = (const float4*)(x + ((size_t)e0 * 7 + t) * 16);
        float xv[16];
        #pragma unroll
        for (int j = 0; j < 4; ++j) {
            float4 v = xp4[j];
            xv[j*4+0] = v.x; xv[j*4+1] = v.y; xv[j*4+2] = v.z; xv[j*4+3] = v.w;
        }
        #pragma unroll
        for (int c = 0; c < 8; ++c) {
            float s = 0.f;
            #pragma unroll
            for (int f = 0; f < 16; ++f) s = fmaf(xv[f], w1s[f * 8 + c], s);
            sA[e * FS + n * 8 + c] = s;
        }
    }
    __syncthreads();

    if (t < 7) {
        float s = 0.f;
        #pragma unroll
        for (int m = 0; m < 7; ++m) s += Ahs[t * 7 + m];
        dinvs[t] = rsqrtf(s);
    }
    __syncthreads();
    if (t < 49) Ahs[t] *= dinvs[t / 7] * dinvs[t % 7];
    __syncthreads();

    // Phase C: h1[e][n] = relu(sum_m A[n,m] y[e][m] + b1)
    #pragma unroll
    for (int c = 0; c < 8; ++c) {
        float s = b1s[c];
        #pragma unroll
        for (int m = 0; m < 7; ++m)
            s = fmaf(Ahs[n * 7 + m], sA[e * FS + m * 8 + c], s);
        sB[e * FS + n * 8 + c] = fmaxf(s, 0.f);
    }
    __syncthreads();   // y dead

    // Phase D1: u[e][m] = h1[e][m] . W2
    {
        float hv[8];
        #pragma unroll
        for (int c = 0; c < 8; ++c) hv[c] = sB[e * FS + n * 8 + c];
        #pragma unroll
        for (int o = 0; o < 8; ++o) {
            float s = 0.f;
            #pragma unroll
            for (int c = 0; c < 8; ++c) s = fmaf(hv[c], w2s[c * 8 + o], s);
            sA[e * FS + n * 8 + o] = s;
        }
    }
    __syncthreads();

    // Phase D2: sflat[e][n] = relu(sum_m A[n,m] u[e][m] + b2)
    #pragma unroll
    for (int o = 0; o < 8; ++o) {
        float s = b2s[o];
        #pragma unroll
        for (int m = 0; m < 7; ++m)
            s = fmaf(Ahs[n * 7 + m], sA[e * FS + m * 8 + o], s);
        sB[e * FS + n * 8 + o] = fmaxf(s, 0.f);
    }
    __syncthreads();

    // Write-out transposed: wave w covers rows j = p*7 + w, fully coalesced.
    #pragma unroll
    for (int p = 0; p < 8; ++p) {
        const int j = p * 7 + wave;   // 0..55
        sflatT[(size_t)j * NB + e0 + lane] = sB[lane * FS + j];
    }
}

// ---------------- Kernel 2: phi MLPs (one k per block, 4 elems/thread) ----
__global__ __launch_bounds__(256, 3)   // VGPR cap ~170; live ~150 -> no spill
void k2_phi(const float* __restrict__ phi_w1, const float* __restrict__ phi_b1,
            const float* __restrict__ phi_w2, const float* __restrict__ phi_b2,
            const float* __restrict__ phi_w3, const float* __restrict__ phi_b3,
            const float* __restrict__ sflatT, float* __restrict__ phsT)
{
    __shared__ float w2s[1024];
    __shared__ float w1s[32], b1s[32], b2s[32], w3s[32];
    __shared__ float b3s;

    const int t = threadIdx.x;
    const int c = blockIdx.x;        // elem chunk 0..31 (1024 elems)
    const int k = blockIdx.y;        // feature net 0..55

    // Stage weights once (coalesced)
    ((float4*)w2s)[t] = ((const float4*)(phi_w2 + k * 1024))[t];
    if (t < 32)            w1s[t]      = phi_w1[k * 32 + t];
    else if (t < 64)       b1s[t - 32] = phi_b1[k * 32 + t - 32];
    else if (t < 96)       b2s[t - 64] = phi_b2[k * 32 + t - 64];
    else if (t < 128)      w3s[t - 96] = phi_w3[k * 32 + t - 96];
    else if (t == 128)     b3s         = phi_b3[k];

    const size_t base = (size_t)k * NB + c * 1024 + t;   // 4 elems per thread
    const float f0 = sflatT[base];
    const float f1 = sflatT[base + 256];
    const float f2 = sflatT[base + 512];
    const float f3 = sflatT[base + 768];
    __syncthreads();

    float p0[32], p1[32], p2[32], p3[32];
    #pragma unroll
    for (int o = 0; o < 32; ++o) { p0[o] = 0.f; p1[o] = 0.f; p2[o] = 0.f; p3[o] = 0.f; }

    #pragma unroll 2
    for (int i = 0; i < 32; ++i) {
        const float w1i = w1s[i], b1i = b1s[i];
        const float a0 = fmaxf(fmaf(f0, w1i, b1i), 0.f);   // phi1 folded
        const float a1 = fmaxf(fmaf(f1, w1i, b1i), 0.f);
        const float a2 = fmaxf(fmaf(f2, w1i, b1i), 0.f);
        const float a3 = fmaxf(fmaf(f3, w1i, b1i), 0.f);
        const float4* wrow = (const float4*)(w2s + i * 32); // broadcast reads
        #pragma unroll
        for (int oc = 0; oc < 8; ++oc) {
            const float4 w4 = wrow[oc];   // 1 ds_read_b128 -> 16 FMAs
            p0[oc*4+0] = fmaf(a0, w4.x, p0[oc*4+0]);
            p0[oc*4+1] = fmaf(a0, w4.y, p0[oc*4+1]);
            p0[oc*4+2] = fmaf(a0, w4.z, p0[oc*4+2]);
            p0[oc*4+3] = fmaf(a0, w4.w, p0[oc*4+3]);
            p1[oc*4+0] = fmaf(a1, w4.x, p1[oc*4+0]);
            p1[oc*4+1] = fmaf(a1, w4.y, p1[oc*4+1]);
            p1[oc*4+2] = fmaf(a1, w4.z, p1[oc*4+2]);
            p1[oc*4+3] = fmaf(a1, w4.w, p1[oc*4+3]);
            p2[oc*4+0] = fmaf(a2, w4.x, p2[oc*4+0]);
            p2[oc*4+1] = fmaf(a2, w4.y, p2[oc*4+1]);
            p2[oc*4+2] = fmaf(a2, w4.z, p2[oc*4+2]);
            p2[oc*4+3] = fmaf(a2, w4.w, p2[oc*4+3]);
            p3[oc*4+0] = fmaf(a3, w4.x, p3[oc*4+0]);
            p3[oc*4+1] = fmaf(a3, w4.y, p3[oc*4+1]);
            p3[oc*4+2] = fmaf(a3, w4.z, p3[oc*4+2]);
            p3[oc*4+3] = fmaf(a3, w4.w, p3[oc*4+3]);
        }
    }

    float ph0 = b3s, ph1 = b3s, ph2 = b3s, ph3 = b3s;
    #pragma unroll
    for (int o = 0; o < 32; ++o) {
        const float w3o = w3s[o], b2o = b2s[o];
        ph0 = fmaf(fmaxf(p0[o] + b2o, 0.f), w3o, ph0);
        ph1 = fmaf(fmaxf(p1[o] + b2o, 0.f), w3o, ph1);
        ph2 = fmaf(fmaxf(p2[o] + b2o, 0.f), w3o, ph2);
        ph3 = fmaf(fmaxf(p3[o] + b2o, 0.f), w3o, ph3);
    }
    phsT[base]       = ph0;
    phsT[base + 256] = ph1;
    phsT[base + 512] = ph2;
    phsT[base + 768] = ph3;
}

// ---------------- Kernel 3: projections + g-MLP + linear head ----------------
// 512 blocks x 256 threads: 64 elems/block (lane = elem), 4 waves split 56 k's.
__global__ __launch_bounds__(256, 2)
void k3_head(const float* __restrict__ g_w1,   const float* __restrict__ g_b1,
             const float* __restrict__ g_w2,   const float* __restrict__ g_b2,
             const float* __restrict__ g_w3,   const float* __restrict__ g_b3,
             const float* __restrict__ line_w1,const float* __restrict__ line_b1,
             const float* __restrict__ line_w2,const float* __restrict__ line_b2,
             const float* __restrict__ sflatT, const float* __restrict__ phsT,
             float* __restrict__ out)
{
    __shared__ float red[4 * 64 * FS];   // 58368 B partials / accs
    __shared__ float gw1s[56 * 32];
    __shared__ float lw1s[56 * 24];
    __shared__ float gw2s[32 * 32];
    __shared__ float gb1s[32], gb2s[32], gw3s[32], lb1s[24], lw2s[24];
    __shared__ float gb3s, lb2s;
    __shared__ float kanp[5 * 64];

    const int t = threadIdx.x;
    const int lane = t & 63, wave = t >> 6;   // 4 waves
    const int e0 = blockIdx.x * 64;

    for (int i = t; i < 1792; i += 256) gw1s[i] = g_w1[i];
    for (int i = t; i < 1344; i += 256) lw1s[i] = line_w1[i];
    for (int i = t; i < 1024; i += 256) gw2s[i] = g_w2[i];
    if (t < 32) { gb1s[t] = g_b1[t]; gb2s[t] = g_b2[t]; gw3s[t] = g_w3[t]; }
    else if (t < 56) { lb1s[t - 32] = line_b1[t - 32]; lw2s[t - 32] = line_w2[t - 32]; }
    else if (t == 56) { gb3s = g_b3[0]; lb2s = line_b2[0]; }
    __syncthreads();

    // each wave: 14 k's; accumulate g1p/l1p for its lane-elem
    float g1p[32], l1p[24];
    #pragma unroll
    for (int j = 0; j < 32; ++j) g1p[j] = 0.f;
    #pragma unroll
    for (int j = 0; j < 24; ++j) l1p[j] = 0.f;

    const int kb = wave * 14;
    #pragma unroll 2
    for (int kk = 0; kk < 14; ++kk) {
        const int k = kb + kk;
        const float ph = phsT[(size_t)k * NB + e0 + lane];   // coalesced
        const float f  = sflatT[(size_t)k * NB + e0 + lane];
        const float4* gr = (const float4*)(gw1s + k * 32);   // broadcast LDS
        #pragma unroll
        for (int jc = 0; jc < 8; ++jc) {
            const float4 w = gr[jc];
            g1p[jc*4+0] = fmaf(ph, w.x, g1p[jc*4+0]);
            g1p[jc*4+1] = fmaf(ph, w.y, g1p[jc*4+1]);
            g1p[jc*4+2] = fmaf(ph, w.z, g1p[jc*4+2]);
            g1p[jc*4+3] = fmaf(ph, w.w, g1p[jc*4+3]);
        }
        const float4* lr = (const float4*)(lw1s + k * 24);   // 96B-aligned
        #pragma unroll
        for (int jc = 0; jc < 6; ++jc) {
            const float4 w = lr[jc];
            l1p[jc*4+0] = fmaf(f, w.x, l1p[jc*4+0]);
            l1p[jc*4+1] = fmaf(f, w.y, l1p[jc*4+1]);
            l1p[jc*4+2] = fmaf(f, w.z, l1p[jc*4+2]);
            l1p[jc*4+3] = fmaf(f, w.w, l1p[jc*4+3]);
        }
    }

    // write partials
    {
        float* my = red + (wave * 64 + lane) * FS;
        #pragma unroll
        for (int j = 0; j < 32; ++j) my[j] = g1p[j];
        #pragma unroll
        for (int j = 0; j < 24; ++j) my[32 + j] = l1p[j];
    }
    __syncthreads();

    // 4-way sum: thread (e = t>>2, g = t&3) handles 14 j's -> red slot 0
    {
        const int e = t >> 2, g = t & 3;
        #pragma unroll
        for (int jj = 0; jj < 14; ++jj) {
            const int j = g * 14 + jj;
            float s = red[(0 * 64 + e) * FS + j] + red[(1 * 64 + e) * FS + j]
                    + red[(2 * 64 + e) * FS + j] + red[(3 * 64 + e) * FS + j];
            red[e * FS + j] = s;
        }
    }
    __syncthreads();

    // tail: waves 0-3 each do 8 of g2's outputs; wave 0 also the linear head
    {
        const float* acc = red + lane * FS;
        float g1[32];
        #pragma unroll
        for (int i = 0; i < 32; ++i) g1[i] = fmaxf(acc[i] + gb1s[i], 0.f);
        const int ob = wave * 8;
        float kp = 0.f;
        #pragma unroll
        for (int oo = 0; oo < 8; ++oo) {
            const int o = ob + oo;
            float s = gb2s[o];
            #pragma unroll
            for (int i = 0; i < 32; ++i) s = fmaf(g1[i], gw2s[i * 32 + o], s);
            kp = fmaf(fmaxf(s, 0.f), gw3s[o], kp);
        }
        kanp[wave * 64 + lane] = kp;
        if (wave == 0) {
            float lin = lb2s;
            #pragma unroll
            for (int j = 0; j < 24; ++j)
                lin = fmaf(fmaxf(acc[32 + j] + lb1s[j], 0.f), lw2s[j], lin);
            kanp[4 * 64 + lane] = lin;
        }
    }
    __syncthreads();

    if (wave == 0) {
        float kan = gb3s + kanp[lane] + kanp[64 + lane]
                  + kanp[128 + lane] + kanp[192 + lane];
        out[e0 + lane] = 0.5f * (kanp[256 + lane] + kan);
    }
}

extern "C" void kernel_launch(void* const* d_in, const int* in_sizes, int n_in,
                              void* d_out, int out_size, void* d_ws, size_t ws_size,
                              hipStream_t stream) {
    const float* x       = (const float*)d_in[0];
    const int*   edge    = (const int*)  d_in[1];
    const float* gcn1_w  = (const float*)d_in[2];
    const float* gcn1_b  = (const float*)d_in[3];
    const float* gcn2_w  = (const float*)d_in[4];
    const float* gcn2_b  = (const float*)d_in[5];
    const float* phi_w1  = (const float*)d_in[6];
    const float* phi_b1  = (const float*)d_in[7];
    const float* phi_w2  = (const float*)d_in[8];
    const float* phi_b2  = (const float*)d_in[9];
    const float* phi_w3  = (const float*)d_in[10];
    const float* phi_b3  = (const float*)d_in[11];
    const float* g_w1    = (const float*)d_in[12];
    const float* g_b1    = (const float*)d_in[13];
    const float* g_w2    = (const float*)d_in[14];
    const float* g_b2    = (const float*)d_in[15];
    const float* g_w3    = (const float*)d_in[16];
    const float* g_b3    = (const float*)d_in[17];
    const float* line_w1 = (const float*)d_in[18];
    const float* line_b1 = (const float*)d_in[19];
    const float* line_w2 = (const float*)d_in[20];
    const float* line_b2 = (const float*)d_in[21];
    float* out = (float*)d_out;

    float* sflatT = (float*)d_ws;                       // [56][NB] = 7.34 MB
    float* phsT   = (float*)d_ws + (size_t)56 * NB;     // [56][NB] = 7.34 MB

    k1_gcn<<<dim3(NB / 64), dim3(448), 0, stream>>>(
        x, edge, gcn1_w, gcn1_b, gcn2_w, gcn2_b, sflatT);

    k2_phi<<<dim3(32, 56), dim3(256), 0, stream>>>(
        phi_w1, phi_b1, phi_w2, phi_b2, phi_w3, phi_b3, sflatT, phsT);

    k3_head<<<dim3(NB / 64), dim3(256), 0, stream>>>(
        g_w1, g_b1, g_w2, g_b2, g_w3, g_b3,
        line_w1, line_b1, line_w2, line_b2, sflatT, phsT, out);
}

// Round 14
// 168.094 us; speedup vs baseline: 1.7622x; 1.0125x over previous
//
#include <hip/hip_runtime.h>

// 3-kernel split. B = 32768.
// K1: GCN (2 layers) -> sflatT [56][B]. Block-id SWIZZLED so the 8 writer
//     blocks of each 512-elem chunk c all dispatch with blk%8 == c%8 -> same
//     XCD L2 as the K2 block that reads chunk c (K2 id = k*64+c, id%8 = c%8).
// K2: 56 per-feature phi MLPs, one k per block, w2 LDS-staged, 2 elems/thread
//     (r10-proven inner, VGPR 60). Round-11 falsified LDS-bound theory (E=4,
//     half the LDS traffic, dur unchanged). Now testing H1: launch-bounds'
//     2nd arg tracked OccupancyPercent (5->47%,4->35%,3->25%) -- drop it.
// K3: projections + g-MLP + head (unchanged).

#define NB 32768
#define FS 57   // 56 + 1 pad

// ---------------- Kernel 1: GCN -> sflatT ----------------
__global__ __launch_bounds__(448, 4)
void k1_gcn(const float* __restrict__ x, const int* __restrict__ edge,
            const float* __restrict__ gcn1_w, const float* __restrict__ gcn1_b,
            const float* __restrict__ gcn2_w, const float* __restrict__ gcn2_b,
            float* __restrict__ sflatT)
{
    __shared__ float sA[64 * FS];    // y, then u
    __shared__ float sB[64 * FS];    // h1, then sflat
    __shared__ float w1s[128], b1s[8], w2s[64], b2s[8];
    __shared__ float Ahs[49], dinvs[7];

    const int t = threadIdx.x;
    const int lane = t & 63, wave = t >> 6;   // 7 waves
    // XCD-align writes with K2 readers: blk = 64q+8s+r -> logical b = 64s+8r+q.
    // Then chunk c (logical blocks 8c..8c+7) is written entirely from
    // dispatch ids with id%8 == c%8 (one XCD's L2).
    const int blk = blockIdx.x;
    const int q = blk >> 6, s = (blk >> 3) & 7, r = blk & 7;
    const int e0 = (64 * s + 8 * r + q) * 64;
    const int e = t / 7, n = t - e * 7;       // t < 448 always

    if (t < 128) w1s[t] = gcn1_w[t];
    else if (t < 192) w2s[t - 128] = gcn2_w[t - 128];
    else if (t < 200) b1s[t - 192] = gcn1_b[t - 192];
    else if (t < 208) b2s[t - 200] = gcn2_b[t - 200];
    else if (t < 257) { int qq = t - 208; Ahs[qq] = ((qq / 7) == (qq % 7)) ? 1.f : 0.f; }
    __syncthreads();
    if (t < 14) Ahs[edge[14 + t] * 7 + edge[t]] = 1.f;   // benign duplicates

    // Phase A: y[e][m][:] = x[e][m][:] . W1   (m == n here)
    {
        const float4* xp4 = (const float4*)(x + ((size_t)e0 * 7 + t) * 16);
        float xv[16];
        #pragma unroll
        for (int j = 0; j < 4; ++j) {
            float4 v = xp4[j];
            xv[j*4+0] = v.x; xv[j*4+1] = v.y; xv[j*4+2] = v.z; xv[j*4+3] = v.w;
        }
        #pragma unroll
        for (int c = 0; c < 8; ++c) {
            float s2 = 0.f;
            #pragma unroll
            for (int f = 0; f < 16; ++f) s2 = fmaf(xv[f], w1s[f * 8 + c], s2);
            sA[e * FS + n * 8 + c] = s2;
        }
    }
    __syncthreads();

    if (t < 7) {
        float s2 = 0.f;
        #pragma unroll
        for (int m = 0; m < 7; ++m) s2 += Ahs[t * 7 + m];
        dinvs[t] = rsqrtf(s2);
    }
    __syncthreads();
    if (t < 49) Ahs[t] *= dinvs[t / 7] * dinvs[t % 7];
    __syncthreads();

    // Phase C: h1[e][n] = relu(sum_m A[n,m] y[e][m] + b1)
    #pragma unroll
    for (int c = 0; c < 8; ++c) {
        float s2 = b1s[c];
        #pragma unroll
        for (int m = 0; m < 7; ++m)
            s2 = fmaf(Ahs[n * 7 + m], sA[e * FS + m * 8 + c], s2);
        sB[e * FS + n * 8 + c] = fmaxf(s2, 0.f);
    }
    __syncthreads();   // y dead

    // Phase D1: u[e][m] = h1[e][m] . W2
    {
        float hv[8];
        #pragma unroll
        for (int c = 0; c < 8; ++c) hv[c] = sB[e * FS + n * 8 + c];
        #pragma unroll
        for (int o = 0; o < 8; ++o) {
            float s2 = 0.f;
            #pragma unroll
            for (int c = 0; c < 8; ++c) s2 = fmaf(hv[c], w2s[c * 8 + o], s2);
            sA[e * FS + n * 8 + o] = s2;
        }
    }
    __syncthreads();

    // Phase D2: sflat[e][n] = relu(sum_m A[n,m] u[e][m] + b2)
    #pragma unroll
    for (int o = 0; o < 8; ++o) {
        float s2 = b2s[o];
        #pragma unroll
        for (int m = 0; m < 7; ++m)
            s2 = fmaf(Ahs[n * 7 + m], sA[e * FS + m * 8 + o], s2);
        sB[e * FS + n * 8 + o] = fmaxf(s2, 0.f);
    }
    __syncthreads();

    // Write-out transposed: wave w covers rows j = p*7 + w, fully coalesced.
    #pragma unroll
    for (int p = 0; p < 8; ++p) {
        const int j = p * 7 + wave;   // 0..55
        sflatT[(size_t)j * NB + e0 + lane] = sB[lane * FS + j];
    }
}

// ---------------- Kernel 2: phi MLPs (one k per block, 2 elems/thread) ----
__global__ __launch_bounds__(256)   // no min-waves arg (H1 test); VGPR free
void k2_phi(const float* __restrict__ phi_w1, const float* __restrict__ phi_b1,
            const float* __restrict__ phi_w2, const float* __restrict__ phi_b2,
            const float* __restrict__ phi_w3, const float* __restrict__ phi_b3,
            const float* __restrict__ sflatT, float* __restrict__ phsT)
{
    __shared__ float w2s[1024];
    __shared__ float w1s[32], b1s[32], b2s[32], w3s[32];
    __shared__ float b3s;

    const int t = threadIdx.x;
    const int c = blockIdx.x;        // elem chunk 0..63
    const int k = blockIdx.y;        // feature net 0..55

    // Stage weights once (coalesced)
    ((float4*)w2s)[t] = ((const float4*)(phi_w2 + k * 1024))[t];
    if (t < 32)            w1s[t]      = phi_w1[k * 32 + t];
    else if (t < 64)       b1s[t - 32] = phi_b1[k * 32 + t - 32];
    else if (t < 96)       b2s[t - 64] = phi_b2[k * 32 + t - 64];
    else if (t < 128)      w3s[t - 96] = phi_w3[k * 32 + t - 96];
    else if (t == 128)     b3s         = phi_b3[k];

    const int eA = c * 512 + t;      // two elems per thread
    const float f0 = sflatT[(size_t)k * NB + eA];
    const float f1 = sflatT[(size_t)k * NB + eA + 256];
    __syncthreads();

    float p2a[32], p2b[32];
    #pragma unroll
    for (int o = 0; o < 32; ++o) { p2a[o] = 0.f; p2b[o] = 0.f; }

    #pragma unroll 2
    for (int i = 0; i < 32; ++i) {
        const float w1i = w1s[i], b1i = b1s[i];
        const float a0 = fmaxf(fmaf(f0, w1i, b1i), 0.f);   // phi1 folded
        const float a1 = fmaxf(fmaf(f1, w1i, b1i), 0.f);
        const float4* wrow = (const float4*)(w2s + i * 32); // broadcast reads
        #pragma unroll
        for (int oc = 0; oc < 8; ++oc) {
            const float4 w4 = wrow[oc];
            p2a[oc*4+0] = fmaf(a0, w4.x, p2a[oc*4+0]);
            p2a[oc*4+1] = fmaf(a0, w4.y, p2a[oc*4+1]);
            p2a[oc*4+2] = fmaf(a0, w4.z, p2a[oc*4+2]);
            p2a[oc*4+3] = fmaf(a0, w4.w, p2a[oc*4+3]);
            p2b[oc*4+0] = fmaf(a1, w4.x, p2b[oc*4+0]);
            p2b[oc*4+1] = fmaf(a1, w4.y, p2b[oc*4+1]);
            p2b[oc*4+2] = fmaf(a1, w4.z, p2b[oc*4+2]);
            p2b[oc*4+3] = fmaf(a1, w4.w, p2b[oc*4+3]);
        }
    }

    float pha = b3s, phb = b3s;
    #pragma unroll
    for (int o = 0; o < 32; ++o) {
        const float w3o = w3s[o], b2o = b2s[o];
        pha = fmaf(fmaxf(p2a[o] + b2o, 0.f), w3o, pha);
        phb = fmaf(fmaxf(p2b[o] + b2o, 0.f), w3o, phb);
    }
    phsT[(size_t)k * NB + eA]       = pha;
    phsT[(size_t)k * NB + eA + 256] = phb;
}

// ---------------- Kernel 3: projections + g-MLP + linear head ----------------
// 512 blocks x 256 threads: 64 elems/block (lane = elem), 4 waves split 56 k's.
__global__ __launch_bounds__(256, 2)
void k3_head(const float* __restrict__ g_w1,   const float* __restrict__ g_b1,
             const float* __restrict__ g_w2,   const float* __restrict__ g_b2,
             const float* __restrict__ g_w3,   const float* __restrict__ g_b3,
             const float* __restrict__ line_w1,const float* __restrict__ line_b1,
             const float* __restrict__ line_w2,const float* __restrict__ line_b2,
             const float* __restrict__ sflatT, const float* __restrict__ phsT,
             float* __restrict__ out)
{
    __shared__ float red[4 * 64 * FS];   // 58368 B partials / accs
    __shared__ float gw1s[56 * 32];
    __shared__ float lw1s[56 * 24];
    __shared__ float gw2s[32 * 32];
    __shared__ float gb1s[32], gb2s[32], gw3s[32], lb1s[24], lw2s[24];
    __shared__ float gb3s, lb2s;
    __shared__ float kanp[5 * 64];

    const int t = threadIdx.x;
    const int lane = t & 63, wave = t >> 6;   // 4 waves
    const int e0 = blockIdx.x * 64;

    for (int i = t; i < 1792; i += 256) gw1s[i] = g_w1[i];
    for (int i = t; i < 1344; i += 256) lw1s[i] = line_w1[i];
    for (int i = t; i < 1024; i += 256) gw2s[i] = g_w2[i];
    if (t < 32) { gb1s[t] = g_b1[t]; gb2s[t] = g_b2[t]; gw3s[t] = g_w3[t]; }
    else if (t < 56) { lb1s[t - 32] = line_b1[t - 32]; lw2s[t - 32] = line_w2[t - 32]; }
    else if (t == 56) { gb3s = g_b3[0]; lb2s = line_b2[0]; }
    __syncthreads();

    // each wave: 14 k's; accumulate g1p/l1p for its lane-elem
    float g1p[32], l1p[24];
    #pragma unroll
    for (int j = 0; j < 32; ++j) g1p[j] = 0.f;
    #pragma unroll
    for (int j = 0; j < 24; ++j) l1p[j] = 0.f;

    const int kb = wave * 14;
    #pragma unroll 2
    for (int kk = 0; kk < 14; ++kk) {
        const int k = kb + kk;
        const float ph = phsT[(size_t)k * NB + e0 + lane];   // coalesced
        const float f  = sflatT[(size_t)k * NB + e0 + lane];
        const float4* gr = (const float4*)(gw1s + k * 32);   // broadcast LDS
        #pragma unroll
        for (int jc = 0; jc < 8; ++jc) {
            const float4 w = gr[jc];
            g1p[jc*4+0] = fmaf(ph, w.x, g1p[jc*4+0]);
            g1p[jc*4+1] = fmaf(ph, w.y, g1p[jc*4+1]);
            g1p[jc*4+2] = fmaf(ph, w.z, g1p[jc*4+2]);
            g1p[jc*4+3] = fmaf(ph, w.w, g1p[jc*4+3]);
        }
        const float4* lr = (const float4*)(lw1s + k * 24);   // 96B-aligned
        #pragma unroll
        for (int jc = 0; jc < 6; ++jc) {
            const float4 w = lr[jc];
            l1p[jc*4+0] = fmaf(f, w.x, l1p[jc*4+0]);
            l1p[jc*4+1] = fmaf(f, w.y, l1p[jc*4+1]);
            l1p[jc*4+2] = fmaf(f, w.z, l1p[jc*4+2]);
            l1p[jc*4+3] = fmaf(f, w.w, l1p[jc*4+3]);
        }
    }

    // write partials
    {
        float* my = red + (wave * 64 + lane) * FS;
        #pragma unroll
        for (int j = 0; j < 32; ++j) my[j] = g1p[j];
        #pragma unroll
        for (int j = 0; j < 24; ++j) my[32 + j] = l1p[j];
    }
    __syncthreads();

    // 4-way sum: thread (e = t>>2, g = t&3) handles 14 j's -> red slot 0
    {
        const int e = t >> 2, g = t & 3;
        #pragma unroll
        for (int jj = 0; jj < 14; ++jj) {
            const int j = g * 14 + jj;
            float s = red[(0 * 64 + e) * FS + j] + red[(1 * 64 + e) * FS + j]
                    + red[(2 * 64 + e) * FS + j] + red[(3 * 64 + e) * FS + j];
            red[e * FS + j] = s;
        }
    }
    __syncthreads();

    // tail: waves 0-3 each do 8 of g2's outputs; wave 0 also the linear head
    {
        const float* acc = red + lane * FS;
        float g1[32];
        #pragma unroll
        for (int i = 0; i < 32; ++i) g1[i] = fmaxf(acc[i] + gb1s[i], 0.f);
        const int ob = wave * 8;
        float kp = 0.f;
        #pragma unroll
        for (int oo = 0; oo < 8; ++oo) {
            const int o = ob + oo;
            float s = gb2s[o];
            #pragma unroll
            for (int i = 0; i < 32; ++i) s = fmaf(g1[i], gw2s[i * 32 + o], s);
            kp = fmaf(fmaxf(s, 0.f), gw3s[o], kp);
        }
        kanp[wave * 64 + lane] = kp;
        if (wave == 0) {
            float lin = lb2s;
            #pragma unroll
            for (int j = 0; j < 24; ++j)
                lin = fmaf(fmaxf(acc[32 + j] + lb1s[j], 0.f), lw2s[j], lin);
            kanp[4 * 64 + lane] = lin;
        }
    }
    __syncthreads();

    if (wave == 0) {
        float kan = gb3s + kanp[lane] + kanp[64 + lane]
                  + kanp[128 + lane] + kanp[192 + lane];
        out[e0 + lane] = 0.5f * (kanp[256 + lane] + kan);
    }
}

extern "C" void kernel_launch(void* const* d_in, const int* in_sizes, int n_in,
                              void* d_out, int out_size, void* d_ws, size_t ws_size,
                              hipStream_t stream) {
    const float* x       = (const float*)d_in[0];
    const int*   edge    = (const int*)  d_in[1];
    const float* gcn1_w  = (const float*)d_in[2];
    const float* gcn1_b  = (const float*)d_in[3];
    const float* gcn2_w  = (const float*)d_in[4];
    const float* gcn2_b  = (const float*)d_in[5];
    const float* phi_w1  = (const float*)d_in[6];
    const float* phi_b1  = (const float*)d_in[7];
    const float* phi_w2  = (const float*)d_in[8];
    const float* phi_b2  = (const float*)d_in[9];
    const float* phi_w3  = (const float*)d_in[10];
    const float* phi_b3  = (const float*)d_in[11];
    const float* g_w1    = (const float*)d_in[12];
    const float* g_b1    = (const float*)d_in[13];
    const float* g_w2    = (const float*)d_in[14];
    const float* g_b2    = (const float*)d_in[15];
    const float* g_w3    = (const float*)d_in[16];
    const float* g_b3    = (const float*)d_in[17];
    const float* line_w1 = (const float*)d_in[18];
    const float* line_b1 = (const float*)d_in[19];
    const float* line_w2 = (const float*)d_in[20];
    const float* line_b2 = (const float*)d_in[21];
    float* out = (float*)d_out;

    float* sflatT = (float*)d_ws;                       // [56][NB] = 7.34 MB
    float* phsT   = (float*)d_ws + (size_t)56 * NB;     // [56][NB] = 7.34 MB

    k1_gcn<<<dim3(NB / 64), dim3(448), 0, stream>>>(
        x, edge, gcn1_w, gcn1_b, gcn2_w, gcn2_b, sflatT);

    k2_phi<<<dim3(64, 56), dim3(256), 0, stream>>>(
        phi_w1, phi_b1, phi_w2, phi_b2, phi_w3, phi_b3, sflatT, phsT);

    k3_head<<<dim3(NB / 64), dim3(256), 0, stream>>>(
        g_w1, g_b1, g_w2, g_b2, g_w3, g_b3,
        line_w1, line_b1, line_w2, line_b2, sflatT, phsT, out);
}